// Round 8
// baseline (986.665 us; speedup 1.0000x reference)
//
#include <hip/hip_runtime.h>
#include <hip/hip_bf16.h>

#define DEV_INLINE __device__ __forceinline__

static constexpr int Nn = 250000;   // nodes
static constexpr int Ee = 1000000;  // edges
static constexpr int Bb = 500;      // graphs
static constexpr int NPB = Nn / Bb; // nodes per graph (batch = repeat(arange(B), N/B))

typedef __attribute__((ext_vector_type(8))) short short8;          // 8 bf16 (4 VGPRs)
typedef __attribute__((ext_vector_type(8))) unsigned short ushort8v;
typedef __attribute__((ext_vector_type(4))) unsigned int uint4v;   // 16B load (4 VGPRs)
typedef __attribute__((ext_vector_type(4))) float f32x4;           // MFMA acc
typedef __attribute__((ext_vector_type(2))) float f32x2;           // packed f32 pair

DEV_INLINE __hip_bfloat16 f2b(float v) { return __float2bfloat16(v); }
DEV_INLINE unsigned short f2bu(float v) {
    __hip_bfloat16 h = __float2bfloat16(v);
    return __builtin_bit_cast(unsigned short, h);
}

// one u32 = two bf16 (elem k low, elem k+1 high) -> two f32, 2 VALU ops
DEV_INLINE f32x2 pairf(unsigned u) {
    f32x2 r;
    r.x = __uint_as_float(u << 16);
    r.y = __uint_as_float(u & 0xffff0000u);
    return r;
}
DEV_INLINE f32x2 fma2(f32x2 a, f32x2 b, f32x2 c) {
#if __has_builtin(__builtin_elementwise_fma)
    return __builtin_elementwise_fma(a, b, c);   // v_pk_fma_f32
#else
    return a * b + c;
#endif
}

// ---------------- degree / dinv / CSR build ----------------
__global__ void k_deg(const int* __restrict__ dst, int* __restrict__ deg) {
    int i = blockIdx.x * 256 + threadIdx.x;
    if (i < Ee) atomicAdd(&deg[dst[i]], 1);
}

__global__ void k_dinv(const int* __restrict__ deg, float* __restrict__ dinv) {
    int i = blockIdx.x * 256 + threadIdx.x;
    if (i < Nn) dinv[i] = rsqrtf((float)deg[i] + 1.0f);
}

__global__ __launch_bounds__(256) void k_scan1(const int* __restrict__ deg,
                                               int* __restrict__ rp,
                                               int* __restrict__ bsum) {
    __shared__ int s[256];
    int t = threadIdx.x;
    int i = blockIdx.x * 256 + t;
    int v = (i < Nn) ? deg[i] : 0;
    s[t] = v;
    __syncthreads();
    for (int off = 1; off < 256; off <<= 1) {
        int x = (t >= off) ? s[t - off] : 0;
        __syncthreads();
        s[t] += x;
        __syncthreads();
    }
    if (i < Nn) rp[i] = s[t] - v;
    if (t == 255) bsum[blockIdx.x] = s[255];
}

__global__ __launch_bounds__(1024) void k_scan2(int* __restrict__ bsum, int nb) {
    __shared__ int s[1024];
    int t = threadIdx.x;
    int v = (t < nb) ? bsum[t] : 0;
    s[t] = v;
    __syncthreads();
    for (int off = 1; off < 1024; off <<= 1) {
        int x = (t >= off) ? s[t - off] : 0;
        __syncthreads();
        s[t] += x;
        __syncthreads();
    }
    if (t < nb) bsum[t] = s[t] - v;
}

__global__ void k_scan3(int* __restrict__ rp, int* __restrict__ cursor,
                        const int* __restrict__ bsum) {
    int i = blockIdx.x * 256 + threadIdx.x;
    if (i < Nn) {
        int v = rp[i] + bsum[blockIdx.x];
        rp[i] = v;
        cursor[i] = v;
    }
    if (i == 0) rp[Nn] = Ee;
}

__global__ void k_scatter(const int* __restrict__ src, const int* __restrict__ dst,
                          const float* __restrict__ dinv, int* __restrict__ cursor,
                          int* __restrict__ col, float* __restrict__ enorm) {
    int i = blockIdx.x * 256 + threadIdx.x;
    if (i >= Ee) return;
    int s = src[i], d = dst[i];
    int pos = atomicAdd(&cursor[d], 1);
    col[pos] = s;
    enorm[pos] = dinv[s] * dinv[d];
}

// ---------------- x (fp32, 78) -> xb (bf16, stride 80, zero-padded) ----------------
__global__ void k_xprep(const float* __restrict__ x, unsigned short* __restrict__ xb) {
    int gid = blockIdx.x * 256 + threadIdx.x; // Nn*20 threads, 4 features each
    if (gid >= Nn * 20) return;
    int i = gid / 20;
    int c = gid - 20 * i;
    int k = 4 * c;
    const float* xp = x + (size_t)i * 78;
    ushort4 u;
    u.x = (k + 0 < 78) ? f2bu(xp[k + 0]) : (unsigned short)0;
    u.y = (k + 1 < 78) ? f2bu(xp[k + 1]) : (unsigned short)0;
    u.z = (k + 2 < 78) ? f2bu(xp[k + 2]) : (unsigned short)0;
    u.w = (k + 3 < 78) ? f2bu(xp[k + 3]) : (unsigned short)0;
    *(ushort4*)&xb[(size_t)i * 80 + k] = u;
}

// ---------------- W -> bf16 B-fragment pack for mfma_f32_16x16x32_bf16 ----------------
// lane l holds B[k = (l>>4)*8 + j + ks*32][n = nt*16 + (l&15)], j=0..7; zero-pad.
template <int K, int F, int KP, int FP>
__global__ __launch_bounds__(64) void k_wprep(const float* __restrict__ W,
                                              unsigned short* __restrict__ Wb) {
    constexpr int KSTEPS = KP / 32;
    const int nt = blockIdx.x, ks = blockIdx.y;
    const int l = threadIdx.x;
    const int n = nt * 16 + (l & 15);
    unsigned short* o = Wb + ((size_t)(nt * KSTEPS + ks) * 64 + l) * 8;
#pragma unroll
    for (int j = 0; j < 8; ++j) {
        const int k = (l >> 4) * 8 + j + ks * 32;
        o[j] = (k < K && n < F) ? f2bu(W[(size_t)k * F + n]) : (unsigned short)0;
    }
}

// ---------------- fused GCN layer: CSR gather (16B/lane) -> bf16 LDS -> MFMA ----------
// in: bf16 rows of stride KIN (zero-padded); out: bf16 rows of stride SOUT (pads zeroed).
// MAXROWS rows per block; NS = MAXROWS*CPR/BD slots per thread, each slot in a
// DIFFERENT row -> NS independent edge chains per thread -> 4*NS non-duplicate
// global loads in flight per round (latency ~1400cy is the binding constraint).
// Accumulate in packed f32 pairs (f32 accum REQUIRED: fp16 accum failed 0.31 absmax).
template <int KIN, int KP, int F, int FP, int SOUT, bool POOL, int MAXROWS>
__global__ __launch_bounds__(320, 6) void k_gcn(const __hip_bfloat16* __restrict__ in_,
                                                const int* __restrict__ rp,
                                                const int* __restrict__ col,
                                                const float* __restrict__ enorm,
                                                const float* __restrict__ dinv,
                                                const unsigned short* __restrict__ Wb,
                                                const float* __restrict__ bias,
                                                __hip_bfloat16* __restrict__ out,
                                                float* __restrict__ gpool) {
    constexpr int BD = 320, WAVES = 5;
    constexpr int CPR = KIN / 8;              // 16B chunks per row
    constexpr int NS = (MAXROWS * CPR) / BD;  // slots (rows) per thread
    constexpr int ECAP = 16 * MAXROWS;
    constexpr int KSTEPS = KP / 32;
    constexpr int NT = FP / 16;
    constexpr int TPW = NT / WAVES;
    static_assert(KIN % 8 == 0 && KP % 32 == 0 && KP >= KIN && FP % (16 * WAVES) == 0, "pad");
    static_assert(MAXROWS % 16 == 0, "row tiles");
    static_assert(MAXROWS * CPR == NS * BD && NS >= 1 && NS <= 2, "slot tiling");
    const unsigned short* in = (const unsigned short*)in_;

    __shared__ alignas(16) unsigned short sh[MAXROWS * KP];
    __shared__ int sRp[MAXROWS + 1];
    __shared__ int sCol[ECAP];
    __shared__ float sEn[ECAP];

    const int i0 = blockIdx.x * MAXROWS;
    const int rows = min(MAXROWS, Nn - i0);       // ragged last block
    const int t = threadIdx.x;
    const int slots = rows * CPR;

    // ---- per-slot setup + hoisted independent self loads (overlap metadata latency) ----
    int rs[NS], cs[NS];
    bool acts[NS];
    uint4v selfv[NS];
    float selfw[NS];
#pragma unroll
    for (int s = 0; s < NS; ++s) {
        const int slot = t + s * BD;
        acts[s] = (slot < slots);
        rs[s] = slot / CPR;
        cs[s] = slot - rs[s] * CPR;
        selfv[s] = uint4v{0u, 0u, 0u, 0u};
        selfw[s] = 0.f;
        if (acts[s]) {
            const int i = i0 + rs[s];
            selfv[s] = *(const uint4v*)(in + (size_t)i * KIN + (size_t)8 * cs[s]);
            const float di = dinv[i];
            selfw[s] = di * di;
        }
    }

    if (t <= rows) sRp[t] = rp[i0 + t];
    const int base = rp[i0];
    const int ne = rp[i0 + rows] - base;
    const bool fit = (ne <= ECAP);
    if (fit) {
        for (int e = t; e < ne; e += BD) {
            sCol[e] = col[base + e];
            sEn[e] = enorm[base + e];
        }
    }
    if constexpr (KP > KIN) { // zero LDS k-pad region
        for (int e = t; e < MAXROWS * (KP - KIN); e += BD) {
            const int rr = e / (KP - KIN);
            sh[rr * KP + KIN + (e - rr * (KP - KIN))] = 0;
        }
    }
    __syncthreads();

    // --- gather: NS independent row-chains per thread, masked 4-wide rounds ---
    f32x2 acc2[NS][4];
    int j[NS], jend[NS];
    int nit = 0;
#pragma unroll
    for (int s = 0; s < NS; ++s) {
#pragma unroll
        for (int q = 0; q < 4; ++q) acc2[s][q] = pairf(selfv[s][q]) * selfw[s];
        j[s] = acts[s] ? (sRp[rs[s]] - base) : 0;
        jend[s] = acts[s] ? (sRp[rs[s] + 1] - base) : 0;
        const int rnd = (jend[s] - j[s] + 3) >> 2;
        nit = max(nit, rnd);
    }

    if (fit) {
        for (int it = 0; it < nit; ++it) {
            int nn[NS][4];
            float wv[NS][4];
#pragma unroll
            for (int s = 0; s < NS; ++s) {
                const int jmc = max(jend[s] - 1, 0);
#pragma unroll
                for (int q = 0; q < 4; ++q) {
                    const int idx = min(j[s] + q, jmc);
                    nn[s][q] = sCol[idx];
                    wv[s][q] = (j[s] + q < jend[s]) ? sEn[idx] : 0.f;
                }
            }
            uint4v a[NS][4];
#pragma unroll
            for (int s = 0; s < NS; ++s)
#pragma unroll
                for (int q = 0; q < 4; ++q)
                    a[s][q] = *(const uint4v*)(in + (size_t)nn[s][q] * KIN + (size_t)8 * cs[s]);
#pragma unroll
            for (int s = 0; s < NS; ++s)
#pragma unroll
                for (int q = 0; q < 4; ++q) {
                    const f32x2 wq = {wv[s][q], wv[s][q]};
#pragma unroll
                    for (int p = 0; p < 4; ++p)
                        acc2[s][p] = fma2(pairf(a[s][q][p]), wq, acc2[s][p]);
                }
#pragma unroll
            for (int s = 0; s < NS; ++s) j[s] += 4;
        }
    } else { // overflow fallback (never for Poisson(4), kept for safety)
#pragma unroll
        for (int s = 0; s < NS; ++s) {
            if (acts[s]) {
                for (int jj = sRp[rs[s]]; jj < sRp[rs[s] + 1]; ++jj) {
                    const int n = col[jj];
                    const float wvv = enorm[jj];
                    const f32x2 wq = {wvv, wvv};
                    uint4v a = *(const uint4v*)(in + (size_t)n * KIN + (size_t)8 * cs[s]);
#pragma unroll
                    for (int p = 0; p < 4; ++p) acc2[s][p] = fma2(pairf(a[p]), wq, acc2[s][p]);
                }
            }
        }
    }

#pragma unroll
    for (int s = 0; s < NS; ++s) {
        if (acts[s]) {
            ushort8v o;
#pragma unroll
            for (int q = 0; q < 4; ++q) {
                o[2 * q + 0] = f2bu(acc2[s][q].x);
                o[2 * q + 1] = f2bu(acc2[s][q].y);
            }
            *(ushort8v*)&sh[rs[s] * KP + 8 * cs[s]] = o;
        }
    }
    __syncthreads();

    // --- MFMA phase: row tiles of 16 ---
    const int w = t >> 6, lane = t & 63;
    const int arow = lane & 15, aquad = lane >> 4;
    const int nrt = rows >> 4;

    for (int rt = 0; rt < nrt; ++rt) {
        short8 afr[KSTEPS];
#pragma unroll
        for (int ks = 0; ks < KSTEPS; ++ks)
            afr[ks] = *(const short8*)&sh[(rt * 16 + arow) * KP + aquad * 8 + ks * 32];

        const int ir0 = i0 + rt * 16;
        const bool uni = (ir0 / NPB) == ((ir0 + 15) / NPB); // tile within one graph

#pragma unroll
        for (int nti = 0; nti < TPW; ++nti) {
            const int nt = w * TPW + nti;
            const short8* bp = (const short8*)Wb + (size_t)nt * KSTEPS * 64 + lane;
            f32x4 acc = {0.f, 0.f, 0.f, 0.f};
#pragma unroll
            for (int ks = 0; ks < KSTEPS; ++ks) {
                short8 bfr = bp[ks * 64];
                acc = __builtin_amdgcn_mfma_f32_16x16x32_bf16(afr[ks], bfr, acc, 0, 0, 0);
            }
            const int f = nt * 16 + arow; // C/D: col = lane&15, row = quad*4 + reg
            const int ib = ir0 + aquad * 4;
            if constexpr (!POOL) {
                if (f < F) {
                    const float bv = bias[f];
#pragma unroll
                    for (int rr = 0; rr < 4; ++rr)
                        out[(size_t)(ib + rr) * SOUT + f] = f2b(fmaxf(acc[rr] + bv, 0.f));
                } else if (f < SOUT) { // zero the pad columns
#pragma unroll
                    for (int rr = 0; rr < 4; ++rr)
                        out[(size_t)(ib + rr) * SOUT + f] = f2b(0.f);
                }
            } else {
                float m = 0.f, v[4];
                const float bv = (f < F) ? bias[f] : 0.f;
#pragma unroll
                for (int rr = 0; rr < 4; ++rr) {
                    v[rr] = fmaxf(acc[rr] + bv, 0.f);
                    m = fmaxf(m, v[rr]);
                }
                if (uni) {
                    // cross-quad max via shuffle (quads = lane blocks of 16), 1 atomic/f/tile
                    m = fmaxf(m, __shfl_xor(m, 16));
                    m = fmaxf(m, __shfl_xor(m, 32));
                    if (aquad == 0 && f < F)
                        atomicMax((int*)&gpool[(ir0 / NPB) * F + f], __float_as_int(m));
                } else if (f < F) {
                    const int g0 = ib / NPB, g3 = (ib + 3) / NPB;
                    if (g0 == g3) {
                        atomicMax((int*)&gpool[g0 * F + f], __float_as_int(m));
                    } else {
#pragma unroll
                        for (int rr = 0; rr < 4; ++rr)
                            atomicMax((int*)&gpool[((ib + rr) / NPB) * F + f], __float_as_int(v[rr]));
                    }
                }
            }
        }
    }
}

// ---------------- FC: grid (FOUT/BD, Bb, KS); block-uniform input row ----------------
template <int K, int FOUT, int KS, bool RELU, int BD>
__global__ __launch_bounds__(BD) void k_fc(const float* __restrict__ in,
                                           const float* __restrict__ W,
                                           const float* __restrict__ bias,
                                           float* __restrict__ out,
                                           int ostride, int ooff) {
    static_assert(!(RELU && KS > 1), "cannot split K with fused ReLU");
    static_assert(K % KS == 0, "K must divide evenly");
    constexpr int KC = K / KS;
    const int j = blockIdx.x * BD + threadIdx.x;
    const int b = blockIdx.y;
    const int z = blockIdx.z;
    const float* __restrict__ inp = in + (size_t)b * K + z * KC;
    const float* __restrict__ Wp = W + (size_t)(z * KC) * FOUT + j;
    float acc = (z == 0) ? bias[j] : 0.f;
#pragma unroll 8
    for (int k = 0; k < KC; ++k) acc += inp[k] * Wp[(size_t)k * FOUT];
    float* dst = &out[(size_t)b * ostride + ooff + j];
    if (KS > 1) {
        atomicAdd(dst, acc);
    } else {
        *dst = RELU ? fmaxf(acc, 0.f) : acc;
    }
}

// ============ protein branch, linearized: xt[b,j] = C0[j] + sum_i T[t[b,i]][i][j] ============
__global__ __launch_bounds__(128) void k_P(const float* __restrict__ emb,
                                           const float* __restrict__ fcxt_w,
                                           float* __restrict__ P) {
    const int v = blockIdx.x, o = blockIdx.y;
    const int j = threadIdx.x;
    __shared__ float se[128];
    se[j] = emb[v * 128 + j];
    __syncthreads();
    float acc[8];
#pragma unroll
    for (int k = 0; k < 8; ++k) acc[k] = 0.f;
    const float* fw = fcxt_w + (size_t)(o * 121) * 128 + j;
#pragma unroll 4
    for (int h = 0; h < 121; ++h) {
        const float f = fw[(size_t)h * 128];
#pragma unroll
        for (int k = 0; k < 8; ++k) acc[k] += se[h + k] * f;
    }
    float* Pp = P + ((size_t)(v * 32 + o) * 8) * 128 + j;
#pragma unroll
    for (int k = 0; k < 8; ++k) Pp[(size_t)k * 128] = acc[k];
}

__global__ __launch_bounds__(128) void k_T(const float* __restrict__ convw,
                                           const float* __restrict__ P,
                                           float* __restrict__ T) {
    const int i0 = blockIdx.x * 8;
    const int v = blockIdx.y;
    const int t = threadIdx.x;
    __shared__ float wt[8 * 256];
    for (int e = t; e < 2048; e += 128) {
        const int r = e >> 8;
        const int kk = e & 255;
        wt[e] = convw[(size_t)(kk >> 3) * 8000 + (size_t)(i0 + r) * 8 + (kk & 7)];
    }
    __syncthreads();
    float acc[8];
#pragma unroll
    for (int r = 0; r < 8; ++r) acc[r] = 0.f;
    const float* Pp = P + (size_t)v * 256 * 128 + t;
#pragma unroll 2
    for (int kk = 0; kk < 256; ++kk) {
        const float pv = Pp[(size_t)kk * 128];
#pragma unroll
        for (int r = 0; r < 8; ++r) acc[r] += wt[r * 256 + kk] * pv;
    }
    float* Tp = T + ((size_t)v * 1000 + i0) * 128 + t;
#pragma unroll
    for (int r = 0; r < 8; ++r) Tp[(size_t)r * 128] = acc[r];
}

__global__ __launch_bounds__(128) void k_C0(const float* __restrict__ fcxt_w,
                                            const float* __restrict__ fcxt_b,
                                            const float* __restrict__ convb,
                                            float* __restrict__ C0) {
    const int o = blockIdx.x;
    const int j = threadIdx.x;
    float acc = 0.f;
    const float* fw = fcxt_w + (size_t)(o * 121) * 128 + j;
#pragma unroll 4
    for (int h = 0; h < 121; ++h) acc += fw[(size_t)h * 128];
    acc *= convb[o];
    if (o == 0) acc += fcxt_b[j];
    atomicAdd(&C0[j], acc);
}

template <int ZS>
__global__ __launch_bounds__(128) void k_xt(const int* __restrict__ target,
                                            const float* __restrict__ T,
                                            const float* __restrict__ C0,
                                            float* __restrict__ xc) {
    constexpr int CH = 1000 / ZS;
    const int b = blockIdx.x;
    const int z = blockIdx.y;
    const int j = threadIdx.x;
    const int* tg = target + b * 1000 + z * CH;
    float acc = (z == 0) ? C0[j] : 0.f;
    int i = 0;
    for (; i + 4 <= CH; i += 4) {
        const int v0 = tg[i + 0], v1 = tg[i + 1], v2 = tg[i + 2], v3 = tg[i + 3];
        const int ib = z * CH + i;
        acc += T[((size_t)v0 * 1000 + ib + 0) * 128 + j]
             + T[((size_t)v1 * 1000 + ib + 1) * 128 + j]
             + T[((size_t)v2 * 1000 + ib + 2) * 128 + j]
             + T[((size_t)v3 * 1000 + ib + 3) * 128 + j];
    }
    for (; i < CH; ++i) { // tail
        acc += T[((size_t)tg[i] * 1000 + z * CH + i) * 128 + j];
    }
    atomicAdd(&xc[(size_t)b * 256 + 128 + j], acc);
}

// ---------------- final projection: one wave per graph, shuffle reduction ----------------
__global__ __launch_bounds__(64) void k_out(const float* __restrict__ in,
                                            const float* __restrict__ w,
                                            const float* __restrict__ ob,
                                            float* __restrict__ out) {
    const int b = blockIdx.x;
    const int lane = threadIdx.x;
    const float* p = in + (size_t)b * 512;
    float acc = 0.f;
#pragma unroll
    for (int i = 0; i < 8; ++i) acc += p[lane + 64 * i] * w[lane + 64 * i];
    for (int off = 32; off > 0; off >>= 1) acc += __shfl_down(acc, off);
    if (lane == 0) out[b] = acc + ob[0];
}

extern "C" void kernel_launch(void* const* d_in, const int* in_sizes, int n_in,
                              void* d_out, int out_size, void* d_ws, size_t ws_size,
                              hipStream_t stream) {
    (void)in_sizes; (void)n_in; (void)out_size; (void)ws_size;
    const float* x      = (const float*)d_in[0];
    const int* ei       = (const int*)d_in[1];
    const int* target   = (const int*)d_in[3];
    const float* W1     = (const float*)d_in[4];
    const float* b1     = (const float*)d_in[5];
    const float* W2     = (const float*)d_in[6];
    const float* b2     = (const float*)d_in[7];
    const float* W3     = (const float*)d_in[8];
    const float* b3     = (const float*)d_in[9];
    const float* fcg1_w = (const float*)d_in[10];
    const float* fcg1_b = (const float*)d_in[11];
    const float* fcg2_w = (const float*)d_in[12];
    const float* fcg2_b = (const float*)d_in[13];
    const float* emb    = (const float*)d_in[14];
    const float* conv_w = (const float*)d_in[15];
    const float* conv_b = (const float*)d_in[16];
    const float* fcxt_w = (const float*)d_in[17];
    const float* fcxt_b = (const float*)d_in[18];
    const float* fc1_w  = (const float*)d_in[19];
    const float* fc1_b  = (const float*)d_in[20];
    const float* fc2_w  = (const float*)d_in[21];
    const float* fc2_b  = (const float*)d_in[22];
    const float* out_w  = (const float*)d_in[23];
    const float* out_b  = (const float*)d_in[24];

    const int* src = ei;
    const int* dst = ei + Ee;

    // ---- workspace layout (~131 MiB; xb aliases h2, head scratch aliases h1) ----
    size_t off = 0;
    auto alloc = [&](size_t bytes) -> void* {
        off = (off + 255) & ~(size_t)255;
        void* p = (char*)d_ws + off;
        off += bytes;
        return p;
    };
    int*   deg    = (int*)alloc((size_t)Nn * 4);
    float* dinv   = (float*)alloc((size_t)Nn * 4);
    int*   rp     = (int*)alloc((size_t)(Nn + 1) * 4);
    int*   col    = (int*)alloc((size_t)Ee * 4);
    float* enorm  = (float*)alloc((size_t)Ee * 4);
    int*   bsum   = (int*)alloc(1024 * 4);
    unsigned short* Wb1 = (unsigned short*)alloc((size_t)5 * 3 * 64 * 8 * 2);
    unsigned short* Wb2 = (unsigned short*)alloc((size_t)10 * 3 * 64 * 8 * 2);
    unsigned short* Wb3 = (unsigned short*)alloc((size_t)20 * 5 * 64 * 8 * 2);
    __hip_bfloat16* h1 = (__hip_bfloat16*)alloc((size_t)Nn * 80 * 2);   // 40 MiB, stride 80
    __hip_bfloat16* h2 = (__hip_bfloat16*)alloc((size_t)Nn * 160 * 2);  // 80 MiB, stride 160
    int* cursor = deg;                     // deg dead after scan1
    unsigned short* xb = (unsigned short*)h2; // xb dead before L2 writes h2

    // head scratch aliases h1 (dead after layer-2 gather)
    size_t hoff = 0;
    auto halloc = [&](size_t bytes) -> void* {
        hoff = (hoff + 255) & ~(size_t)255;
        void* p = (char*)h1 + hoff;
        hoff += bytes;
        return p;
    };
    float* gpool = (float*)halloc((size_t)Bb * 312 * 4);
    float* g1    = (float*)halloc((size_t)Bb * 1024 * 4);
    float* xc    = (float*)halloc((size_t)Bb * 256 * 4);
    float* f1    = (float*)halloc((size_t)Bb * 1024 * 4);
    float* f2    = (float*)halloc((size_t)Bb * 512 * 4);
    float* C0    = (float*)halloc(128 * 4);
    float* Pbuf  = (float*)halloc((size_t)26 * 32 * 8 * 128 * 4);
    float* Tbuf  = (float*)halloc((size_t)26 * 1000 * 128 * 4);

    const int nb = (Nn + 255) / 256; // 977

    // x -> bf16 padded (into h2 region; consumed by L1 before h2 written)
    k_xprep<<<(Nn * 20 + 255) / 256, 256, 0, stream>>>(x, xb);

    // degree + dinv + CSR (by dst)
    hipMemsetAsync(deg, 0, (size_t)Nn * 4, stream);
    k_deg<<<(Ee + 255) / 256, 256, 0, stream>>>(dst, deg);
    k_dinv<<<nb, 256, 0, stream>>>(deg, dinv);
    k_scan1<<<nb, 256, 0, stream>>>(deg, rp, bsum);
    k_scan2<<<1, 1024, 0, stream>>>(bsum, nb);
    k_scan3<<<nb, 256, 0, stream>>>(rp, cursor, bsum);
    k_scatter<<<(Ee + 255) / 256, 256, 0, stream>>>(src, dst, dinv, cursor, col, enorm);

    // pack W into MFMA B-fragment layout (tiny)
    k_wprep<78, 78, 96, 80><<<dim3(5, 3), 64, 0, stream>>>(W1, Wb1);
    k_wprep<78, 156, 96, 160><<<dim3(10, 3), 64, 0, stream>>>(W2, Wb2);
    k_wprep<156, 312, 160, 320><<<dim3(20, 5), 64, 0, stream>>>(W3, Wb3);

    // GCN layers (gather -> MFMA; layer 3 fuses max-pool); NS=2 slots/thread
    const int g64 = (Nn + 63) / 64; // 3907 (last block ragged: 16 rows)
    const int g32 = (Nn + 31) / 32; // 7813 (last block ragged: 16 rows)
    k_gcn<80, 96, 78, 80, 80, false, 64><<<g64, 320, 0, stream>>>(
        (const __hip_bfloat16*)xb, rp, col, enorm, dinv, Wb1, b1, h1, (float*)nullptr);
    k_gcn<80, 96, 156, 160, 160, false, 64><<<g64, 320, 0, stream>>>(
        h1, rp, col, enorm, dinv, Wb2, b2, h2, (float*)nullptr);
    // ---- h1 dead from here; alias region becomes head scratch ----
    hipMemsetAsync(gpool, 0, (size_t)Bb * 312 * 4, stream);
    k_gcn<160, 160, 312, 320, 0, true, 32><<<g32, 320, 0, stream>>>(
        h2, rp, col, enorm, dinv, Wb3, b3, (__hip_bfloat16*)nullptr, gpool);

    // protein branch (linearized)
    hipMemsetAsync(C0, 0, 128 * 4, stream);
    hipMemsetAsync(xc, 0, (size_t)Bb * 256 * 4, stream);
    k_P<<<dim3(26, 32), 128, 0, stream>>>(emb, fcxt_w, Pbuf);
    k_T<<<dim3(125, 26), 128, 0, stream>>>(conv_w, Pbuf, Tbuf);
    k_C0<<<32, 128, 0, stream>>>(fcxt_w, fcxt_b, conv_b, C0);
    k_xt<8><<<dim3(Bb, 8), 128, 0, stream>>>(target, Tbuf, C0, xc);

    // graph head
    k_fc<312, 1024, 1, true, 256><<<dim3(4, Bb, 1), 256, 0, stream>>>(gpool, fcg1_w, fcg1_b, g1, 1024, 0);
    k_fc<1024, 128, 2, false, 128><<<dim3(1, Bb, 2), 128, 0, stream>>>(g1, fcg2_w, fcg2_b, xc, 256, 0);

    // fusion head
    k_fc<256, 1024, 1, true, 256><<<dim3(4, Bb, 1), 256, 0, stream>>>(xc, fc1_w, fc1_b, f1, 1024, 0);
    k_fc<1024, 512, 1, true, 256><<<dim3(2, Bb, 1), 256, 0, stream>>>(f1, fc2_w, fc2_b, f2, 512, 0);
    k_out<<<Bb, 64, 0, stream>>>(f2, out_w, out_b, (float*)d_out);
}

// Round 9
// 942.202 us; speedup vs baseline: 1.0472x; 1.0472x over previous
//
#include <hip/hip_runtime.h>
#include <hip/hip_bf16.h>

#define DEV_INLINE __device__ __forceinline__

static constexpr int Nn = 250000;   // nodes
static constexpr int Ee = 1000000;  // edges
static constexpr int Bb = 500;      // graphs
static constexpr int NPB = Nn / Bb; // nodes per graph (batch = repeat(arange(B), N/B))

typedef __attribute__((ext_vector_type(8))) short short8;          // 8 bf16 (4 VGPRs)
typedef __attribute__((ext_vector_type(8))) unsigned short ushort8v;
typedef __attribute__((ext_vector_type(4))) unsigned int uint4v;   // 16B load (4 VGPRs)
typedef __attribute__((ext_vector_type(4))) float f32x4;           // MFMA acc
typedef __attribute__((ext_vector_type(2))) float f32x2;           // packed f32 pair

DEV_INLINE __hip_bfloat16 f2b(float v) { return __float2bfloat16(v); }
DEV_INLINE unsigned short f2bu(float v) {
    __hip_bfloat16 h = __float2bfloat16(v);
    return __builtin_bit_cast(unsigned short, h);
}

// one u32 = two bf16 (elem k low, elem k+1 high) -> two f32, 2 VALU ops
DEV_INLINE f32x2 pairf(unsigned u) {
    f32x2 r;
    r.x = __uint_as_float(u << 16);
    r.y = __uint_as_float(u & 0xffff0000u);
    return r;
}
DEV_INLINE f32x2 fma2(f32x2 a, f32x2 b, f32x2 c) {
#if __has_builtin(__builtin_elementwise_fma)
    return __builtin_elementwise_fma(a, b, c);   // v_pk_fma_f32
#else
    return a * b + c;
#endif
}

// ---------------- degree / dinv / CSR build ----------------
__global__ void k_deg(const int* __restrict__ dst, int* __restrict__ deg) {
    int i = blockIdx.x * 256 + threadIdx.x;
    if (i < Ee) atomicAdd(&deg[dst[i]], 1);
}

__global__ void k_dinv(const int* __restrict__ deg, float* __restrict__ dinv) {
    int i = blockIdx.x * 256 + threadIdx.x;
    if (i < Nn) dinv[i] = rsqrtf((float)deg[i] + 1.0f);
}

__global__ __launch_bounds__(256) void k_scan1(const int* __restrict__ deg,
                                               int* __restrict__ rp,
                                               int* __restrict__ bsum) {
    __shared__ int s[256];
    int t = threadIdx.x;
    int i = blockIdx.x * 256 + t;
    int v = (i < Nn) ? deg[i] : 0;
    s[t] = v;
    __syncthreads();
    for (int off = 1; off < 256; off <<= 1) {
        int x = (t >= off) ? s[t - off] : 0;
        __syncthreads();
        s[t] += x;
        __syncthreads();
    }
    if (i < Nn) rp[i] = s[t] - v;
    if (t == 255) bsum[blockIdx.x] = s[255];
}

__global__ __launch_bounds__(1024) void k_scan2(int* __restrict__ bsum, int nb) {
    __shared__ int s[1024];
    int t = threadIdx.x;
    int v = (t < nb) ? bsum[t] : 0;
    s[t] = v;
    __syncthreads();
    for (int off = 1; off < 1024; off <<= 1) {
        int x = (t >= off) ? s[t - off] : 0;
        __syncthreads();
        s[t] += x;
        __syncthreads();
    }
    if (t < nb) bsum[t] = s[t] - v;
}

__global__ void k_scan3(int* __restrict__ rp, int* __restrict__ cursor,
                        const int* __restrict__ bsum) {
    int i = blockIdx.x * 256 + threadIdx.x;
    if (i < Nn) {
        int v = rp[i] + bsum[blockIdx.x];
        rp[i] = v;
        cursor[i] = v;
    }
    if (i == 0) rp[Nn] = Ee;
}

__global__ void k_scatter(const int* __restrict__ src, const int* __restrict__ dst,
                          const float* __restrict__ dinv, int* __restrict__ cursor,
                          int* __restrict__ col, float* __restrict__ enorm) {
    int i = blockIdx.x * 256 + threadIdx.x;
    if (i >= Ee) return;
    int s = src[i], d = dst[i];
    int pos = atomicAdd(&cursor[d], 1);
    col[pos] = s;
    enorm[pos] = dinv[s] * dinv[d];
}

// ---------------- x (fp32, 78) -> xb (bf16, stride 80, zero-padded) ----------------
__global__ void k_xprep(const float* __restrict__ x, unsigned short* __restrict__ xb) {
    int gid = blockIdx.x * 256 + threadIdx.x; // Nn*20 threads, 4 features each
    if (gid >= Nn * 20) return;
    int i = gid / 20;
    int c = gid - 20 * i;
    int k = 4 * c;
    const float* xp = x + (size_t)i * 78;
    ushort4 u;
    u.x = (k + 0 < 78) ? f2bu(xp[k + 0]) : (unsigned short)0;
    u.y = (k + 1 < 78) ? f2bu(xp[k + 1]) : (unsigned short)0;
    u.z = (k + 2 < 78) ? f2bu(xp[k + 2]) : (unsigned short)0;
    u.w = (k + 3 < 78) ? f2bu(xp[k + 3]) : (unsigned short)0;
    *(ushort4*)&xb[(size_t)i * 80 + k] = u;
}

// ---------------- W -> bf16 B-fragment pack for mfma_f32_16x16x32_bf16 ----------------
// lane l holds B[k = (l>>4)*8 + j + ks*32][n = nt*16 + (l&15)], j=0..7; zero-pad.
template <int K, int F, int KP, int FP>
__global__ __launch_bounds__(64) void k_wprep(const float* __restrict__ W,
                                              unsigned short* __restrict__ Wb) {
    constexpr int KSTEPS = KP / 32;
    const int nt = blockIdx.x, ks = blockIdx.y;
    const int l = threadIdx.x;
    const int n = nt * 16 + (l & 15);
    unsigned short* o = Wb + ((size_t)(nt * KSTEPS + ks) * 64 + l) * 8;
#pragma unroll
    for (int j = 0; j < 8; ++j) {
        const int k = (l >> 4) * 8 + j + ks * 32;
        o[j] = (k < K && n < F) ? f2bu(W[(size_t)k * F + n]) : (unsigned short)0;
    }
}

// ---------------- fused GCN layer: CSR gather (16B/lane) -> bf16 LDS -> MFMA ----------
// in: bf16 rows of stride KIN (zero-padded); out: bf16 rows of stride SOUT (pads zeroed).
// MAXROWS rows per block; NS = MAXROWS*CPR/BD slots per thread, each slot in a
// DIFFERENT row -> NS independent edge chains per thread -> 4*NS non-duplicate
// loads in flight per round. Masked-out lanes load node 0 (L1/L2-hot everywhere)
// instead of stale clamped addresses -> no redundant HBM traffic.
// launch_bounds(320,4): VGPR cap 128 -- (320,6)'s cap caused scratch spill (r8:
// WRITE_SIZE 21->460 MB). f32 accumulation REQUIRED (fp16 accum: 0.31 absmax).
template <int KIN, int KP, int F, int FP, int SOUT, bool POOL, int MAXROWS>
__global__ __launch_bounds__(320, 4) void k_gcn(const __hip_bfloat16* __restrict__ in_,
                                                const int* __restrict__ rp,
                                                const int* __restrict__ col,
                                                const float* __restrict__ enorm,
                                                const float* __restrict__ dinv,
                                                const unsigned short* __restrict__ Wb,
                                                const float* __restrict__ bias,
                                                __hip_bfloat16* __restrict__ out,
                                                float* __restrict__ gpool) {
    constexpr int BD = 320, WAVES = 5;
    constexpr int CPR = KIN / 8;              // 16B chunks per row
    constexpr int NS = (MAXROWS * CPR) / BD;  // slots (rows) per thread
    constexpr int ECAP = 16 * MAXROWS;
    constexpr int KSTEPS = KP / 32;
    constexpr int NT = FP / 16;
    constexpr int TPW = NT / WAVES;
    static_assert(KIN % 8 == 0 && KP % 32 == 0 && KP >= KIN && FP % (16 * WAVES) == 0, "pad");
    static_assert(MAXROWS % 16 == 0, "row tiles");
    static_assert(MAXROWS * CPR == NS * BD && NS >= 1 && NS <= 2, "slot tiling");
    const unsigned short* in = (const unsigned short*)in_;

    __shared__ alignas(16) unsigned short sh[MAXROWS * KP];
    __shared__ int sRp[MAXROWS + 1];
    __shared__ int sCol[ECAP];
    __shared__ float sEn[ECAP];

    const int i0 = blockIdx.x * MAXROWS;
    const int rows = min(MAXROWS, Nn - i0);       // ragged last block
    const int t = threadIdx.x;
    const int slots = rows * CPR;

    // ---- per-slot setup + hoisted independent self loads (overlap metadata latency) ----
    int rs[NS], cs[NS];
    bool acts[NS];
    uint4v selfv[NS];
    float selfw[NS];
#pragma unroll
    for (int s = 0; s < NS; ++s) {
        const int slot = t + s * BD;
        acts[s] = (slot < slots);
        rs[s] = slot / CPR;
        cs[s] = slot - rs[s] * CPR;
        selfv[s] = uint4v{0u, 0u, 0u, 0u};
        selfw[s] = 0.f;
        if (acts[s]) {
            const int i = i0 + rs[s];
            selfv[s] = *(const uint4v*)(in + (size_t)i * KIN + (size_t)8 * cs[s]);
            const float di = dinv[i];
            selfw[s] = di * di;
        }
    }

    if (t <= rows) sRp[t] = rp[i0 + t];
    const int base = rp[i0];
    const int ne = rp[i0 + rows] - base;
    const bool fit = (ne <= ECAP);
    if (fit) {
        for (int e = t; e < ne; e += BD) {
            sCol[e] = col[base + e];
            sEn[e] = enorm[base + e];
        }
    }
    if constexpr (KP > KIN) { // zero LDS k-pad region
        for (int e = t; e < MAXROWS * (KP - KIN); e += BD) {
            const int rr = e / (KP - KIN);
            sh[rr * KP + KIN + (e - rr * (KP - KIN))] = 0;
        }
    }
    __syncthreads();

    // --- gather: NS independent row-chains per thread, masked 4-wide rounds ---
    f32x2 acc2[NS][4];
    int j[NS], jend[NS];
    int nit = 0;
#pragma unroll
    for (int s = 0; s < NS; ++s) {
#pragma unroll
        for (int q = 0; q < 4; ++q) acc2[s][q] = pairf(selfv[s][q]) * selfw[s];
        j[s] = acts[s] ? (sRp[rs[s]] - base) : 0;
        jend[s] = acts[s] ? (sRp[rs[s] + 1] - base) : 0;
        const int rnd = (jend[s] - j[s] + 3) >> 2;
        nit = max(nit, rnd);
    }

    if (fit) {
        for (int it = 0; it < nit; ++it) {
            int nn[NS][4];
            float wv[NS][4];
#pragma unroll
            for (int s = 0; s < NS; ++s) {
                const int jmc = max(jend[s] - 1, 0);
#pragma unroll
                for (int q = 0; q < 4; ++q) {
                    const bool on = (j[s] + q < jend[s]);
                    const int idx = min(j[s] + q, jmc);
                    nn[s][q] = on ? sCol[idx] : 0;   // inactive -> node 0 (cache-hot)
                    wv[s][q] = on ? sEn[idx] : 0.f;
                }
            }
            uint4v a[NS][4];
#pragma unroll
            for (int s = 0; s < NS; ++s)
#pragma unroll
                for (int q = 0; q < 4; ++q)
                    a[s][q] = *(const uint4v*)(in + (size_t)nn[s][q] * KIN + (size_t)8 * cs[s]);
#pragma unroll
            for (int s = 0; s < NS; ++s)
#pragma unroll
                for (int q = 0; q < 4; ++q) {
                    const f32x2 wq = {wv[s][q], wv[s][q]};
#pragma unroll
                    for (int p = 0; p < 4; ++p)
                        acc2[s][p] = fma2(pairf(a[s][q][p]), wq, acc2[s][p]);
                }
#pragma unroll
            for (int s = 0; s < NS; ++s) j[s] += 4;
        }
    } else { // overflow fallback (never for Poisson(4), kept for safety)
#pragma unroll
        for (int s = 0; s < NS; ++s) {
            if (acts[s]) {
                for (int jj = sRp[rs[s]]; jj < sRp[rs[s] + 1]; ++jj) {
                    const int n = col[jj];
                    const float wvv = enorm[jj];
                    const f32x2 wq = {wvv, wvv};
                    uint4v a = *(const uint4v*)(in + (size_t)n * KIN + (size_t)8 * cs[s]);
#pragma unroll
                    for (int p = 0; p < 4; ++p) acc2[s][p] = fma2(pairf(a[p]), wq, acc2[s][p]);
                }
            }
        }
    }

#pragma unroll
    for (int s = 0; s < NS; ++s) {
        if (acts[s]) {
            ushort8v o;
#pragma unroll
            for (int q = 0; q < 4; ++q) {
                o[2 * q + 0] = f2bu(acc2[s][q].x);
                o[2 * q + 1] = f2bu(acc2[s][q].y);
            }
            *(ushort8v*)&sh[rs[s] * KP + 8 * cs[s]] = o;
        }
    }
    __syncthreads();

    // --- MFMA phase: row tiles of 16 ---
    const int w = t >> 6, lane = t & 63;
    const int arow = lane & 15, aquad = lane >> 4;
    const int nrt = rows >> 4;

    for (int rt = 0; rt < nrt; ++rt) {
        short8 afr[KSTEPS];
#pragma unroll
        for (int ks = 0; ks < KSTEPS; ++ks)
            afr[ks] = *(const short8*)&sh[(rt * 16 + arow) * KP + aquad * 8 + ks * 32];

        const int ir0 = i0 + rt * 16;
        const bool uni = (ir0 / NPB) == ((ir0 + 15) / NPB); // tile within one graph

#pragma unroll
        for (int nti = 0; nti < TPW; ++nti) {
            const int nt = w * TPW + nti;
            const short8* bp = (const short8*)Wb + (size_t)nt * KSTEPS * 64 + lane;
            f32x4 acc = {0.f, 0.f, 0.f, 0.f};
#pragma unroll
            for (int ks = 0; ks < KSTEPS; ++ks) {
                short8 bfr = bp[ks * 64];
                acc = __builtin_amdgcn_mfma_f32_16x16x32_bf16(afr[ks], bfr, acc, 0, 0, 0);
            }
            const int f = nt * 16 + arow; // C/D: col = lane&15, row = quad*4 + reg
            const int ib = ir0 + aquad * 4;
            if constexpr (!POOL) {
                if (f < F) {
                    const float bv = bias[f];
#pragma unroll
                    for (int rr = 0; rr < 4; ++rr)
                        out[(size_t)(ib + rr) * SOUT + f] = f2b(fmaxf(acc[rr] + bv, 0.f));
                } else if (f < SOUT) { // zero the pad columns
#pragma unroll
                    for (int rr = 0; rr < 4; ++rr)
                        out[(size_t)(ib + rr) * SOUT + f] = f2b(0.f);
                }
            } else {
                float m = 0.f, v[4];
                const float bv = (f < F) ? bias[f] : 0.f;
#pragma unroll
                for (int rr = 0; rr < 4; ++rr) {
                    v[rr] = fmaxf(acc[rr] + bv, 0.f);
                    m = fmaxf(m, v[rr]);
                }
                if (uni) {
                    // cross-quad max via shuffle (quads = lane blocks of 16), 1 atomic/f/tile
                    m = fmaxf(m, __shfl_xor(m, 16));
                    m = fmaxf(m, __shfl_xor(m, 32));
                    if (aquad == 0 && f < F)
                        atomicMax((int*)&gpool[(ir0 / NPB) * F + f], __float_as_int(m));
                } else if (f < F) {
                    const int g0 = ib / NPB, g3 = (ib + 3) / NPB;
                    if (g0 == g3) {
                        atomicMax((int*)&gpool[g0 * F + f], __float_as_int(m));
                    } else {
#pragma unroll
                        for (int rr = 0; rr < 4; ++rr)
                            atomicMax((int*)&gpool[((ib + rr) / NPB) * F + f], __float_as_int(v[rr]));
                    }
                }
            }
        }
    }
}

// ---------------- FC: grid (FOUT/BD, Bb, KS); block-uniform input row ----------------
template <int K, int FOUT, int KS, bool RELU, int BD>
__global__ __launch_bounds__(BD) void k_fc(const float* __restrict__ in,
                                           const float* __restrict__ W,
                                           const float* __restrict__ bias,
                                           float* __restrict__ out,
                                           int ostride, int ooff) {
    static_assert(!(RELU && KS > 1), "cannot split K with fused ReLU");
    static_assert(K % KS == 0, "K must divide evenly");
    constexpr int KC = K / KS;
    const int j = blockIdx.x * BD + threadIdx.x;
    const int b = blockIdx.y;
    const int z = blockIdx.z;
    const float* __restrict__ inp = in + (size_t)b * K + z * KC;
    const float* __restrict__ Wp = W + (size_t)(z * KC) * FOUT + j;
    float acc = (z == 0) ? bias[j] : 0.f;
#pragma unroll 8
    for (int k = 0; k < KC; ++k) acc += inp[k] * Wp[(size_t)k * FOUT];
    float* dst = &out[(size_t)b * ostride + ooff + j];
    if (KS > 1) {
        atomicAdd(dst, acc);
    } else {
        *dst = RELU ? fmaxf(acc, 0.f) : acc;
    }
}

// ============ protein branch, linearized: xt[b,j] = C0[j] + sum_i T[t[b,i]][i][j] ============
__global__ __launch_bounds__(128) void k_P(const float* __restrict__ emb,
                                           const float* __restrict__ fcxt_w,
                                           float* __restrict__ P) {
    const int v = blockIdx.x, o = blockIdx.y;
    const int j = threadIdx.x;
    __shared__ float se[128];
    se[j] = emb[v * 128 + j];
    __syncthreads();
    float acc[8];
#pragma unroll
    for (int k = 0; k < 8; ++k) acc[k] = 0.f;
    const float* fw = fcxt_w + (size_t)(o * 121) * 128 + j;
#pragma unroll 4
    for (int h = 0; h < 121; ++h) {
        const float f = fw[(size_t)h * 128];
#pragma unroll
        for (int k = 0; k < 8; ++k) acc[k] += se[h + k] * f;
    }
    float* Pp = P + ((size_t)(v * 32 + o) * 8) * 128 + j;
#pragma unroll
    for (int k = 0; k < 8; ++k) Pp[(size_t)k * 128] = acc[k];
}

__global__ __launch_bounds__(128) void k_T(const float* __restrict__ convw,
                                           const float* __restrict__ P,
                                           float* __restrict__ T) {
    const int i0 = blockIdx.x * 8;
    const int v = blockIdx.y;
    const int t = threadIdx.x;
    __shared__ float wt[8 * 256];
    for (int e = t; e < 2048; e += 128) {
        const int r = e >> 8;
        const int kk = e & 255;
        wt[e] = convw[(size_t)(kk >> 3) * 8000 + (size_t)(i0 + r) * 8 + (kk & 7)];
    }
    __syncthreads();
    float acc[8];
#pragma unroll
    for (int r = 0; r < 8; ++r) acc[r] = 0.f;
    const float* Pp = P + (size_t)v * 256 * 128 + t;
#pragma unroll 2
    for (int kk = 0; kk < 256; ++kk) {
        const float pv = Pp[(size_t)kk * 128];
#pragma unroll
        for (int r = 0; r < 8; ++r) acc[r] += wt[r * 256 + kk] * pv;
    }
    float* Tp = T + ((size_t)v * 1000 + i0) * 128 + t;
#pragma unroll
    for (int r = 0; r < 8; ++r) Tp[(size_t)r * 128] = acc[r];
}

__global__ __launch_bounds__(128) void k_C0(const float* __restrict__ fcxt_w,
                                            const float* __restrict__ fcxt_b,
                                            const float* __restrict__ convb,
                                            float* __restrict__ C0) {
    const int o = blockIdx.x;
    const int j = threadIdx.x;
    float acc = 0.f;
    const float* fw = fcxt_w + (size_t)(o * 121) * 128 + j;
#pragma unroll 4
    for (int h = 0; h < 121; ++h) acc += fw[(size_t)h * 128];
    acc *= convb[o];
    if (o == 0) acc += fcxt_b[j];
    atomicAdd(&C0[j], acc);
}

template <int ZS>
__global__ __launch_bounds__(128) void k_xt(const int* __restrict__ target,
                                            const float* __restrict__ T,
                                            const float* __restrict__ C0,
                                            float* __restrict__ xc) {
    constexpr int CH = 1000 / ZS;
    const int b = blockIdx.x;
    const int z = blockIdx.y;
    const int j = threadIdx.x;
    const int* tg = target + b * 1000 + z * CH;
    float acc = (z == 0) ? C0[j] : 0.f;
    int i = 0;
    for (; i + 4 <= CH; i += 4) {
        const int v0 = tg[i + 0], v1 = tg[i + 1], v2 = tg[i + 2], v3 = tg[i + 3];
        const int ib = z * CH + i;
        acc += T[((size_t)v0 * 1000 + ib + 0) * 128 + j]
             + T[((size_t)v1 * 1000 + ib + 1) * 128 + j]
             + T[((size_t)v2 * 1000 + ib + 2) * 128 + j]
             + T[((size_t)v3 * 1000 + ib + 3) * 128 + j];
    }
    for (; i < CH; ++i) { // tail
        acc += T[((size_t)tg[i] * 1000 + z * CH + i) * 128 + j];
    }
    atomicAdd(&xc[(size_t)b * 256 + 128 + j], acc);
}

// ---------------- final projection: one wave per graph, shuffle reduction ----------------
__global__ __launch_bounds__(64) void k_out(const float* __restrict__ in,
                                            const float* __restrict__ w,
                                            const float* __restrict__ ob,
                                            float* __restrict__ out) {
    const int b = blockIdx.x;
    const int lane = threadIdx.x;
    const float* p = in + (size_t)b * 512;
    float acc = 0.f;
#pragma unroll
    for (int i = 0; i < 8; ++i) acc += p[lane + 64 * i] * w[lane + 64 * i];
    for (int off = 32; off > 0; off >>= 1) acc += __shfl_down(acc, off);
    if (lane == 0) out[b] = acc + ob[0];
}

extern "C" void kernel_launch(void* const* d_in, const int* in_sizes, int n_in,
                              void* d_out, int out_size, void* d_ws, size_t ws_size,
                              hipStream_t stream) {
    (void)in_sizes; (void)n_in; (void)out_size; (void)ws_size;
    const float* x      = (const float*)d_in[0];
    const int* ei       = (const int*)d_in[1];
    const int* target   = (const int*)d_in[3];
    const float* W1     = (const float*)d_in[4];
    const float* b1     = (const float*)d_in[5];
    const float* W2     = (const float*)d_in[6];
    const float* b2     = (const float*)d_in[7];
    const float* W3     = (const float*)d_in[8];
    const float* b3     = (const float*)d_in[9];
    const float* fcg1_w = (const float*)d_in[10];
    const float* fcg1_b = (const float*)d_in[11];
    const float* fcg2_w = (const float*)d_in[12];
    const float* fcg2_b = (const float*)d_in[13];
    const float* emb    = (const float*)d_in[14];
    const float* conv_w = (const float*)d_in[15];
    const float* conv_b = (const float*)d_in[16];
    const float* fcxt_w = (const float*)d_in[17];
    const float* fcxt_b = (const float*)d_in[18];
    const float* fc1_w  = (const float*)d_in[19];
    const float* fc1_b  = (const float*)d_in[20];
    const float* fc2_w  = (const float*)d_in[21];
    const float* fc2_b  = (const float*)d_in[22];
    const float* out_w  = (const float*)d_in[23];
    const float* out_b  = (const float*)d_in[24];

    const int* src = ei;
    const int* dst = ei + Ee;

    // ---- workspace layout (~131 MiB; xb aliases h2, head scratch aliases h1) ----
    size_t off = 0;
    auto alloc = [&](size_t bytes) -> void* {
        off = (off + 255) & ~(size_t)255;
        void* p = (char*)d_ws + off;
        off += bytes;
        return p;
    };
    int*   deg    = (int*)alloc((size_t)Nn * 4);
    float* dinv   = (float*)alloc((size_t)Nn * 4);
    int*   rp     = (int*)alloc((size_t)(Nn + 1) * 4);
    int*   col    = (int*)alloc((size_t)Ee * 4);
    float* enorm  = (float*)alloc((size_t)Ee * 4);
    int*   bsum   = (int*)alloc(1024 * 4);
    unsigned short* Wb1 = (unsigned short*)alloc((size_t)5 * 3 * 64 * 8 * 2);
    unsigned short* Wb2 = (unsigned short*)alloc((size_t)10 * 3 * 64 * 8 * 2);
    unsigned short* Wb3 = (unsigned short*)alloc((size_t)20 * 5 * 64 * 8 * 2);
    __hip_bfloat16* h1 = (__hip_bfloat16*)alloc((size_t)Nn * 80 * 2);   // 40 MiB, stride 80
    __hip_bfloat16* h2 = (__hip_bfloat16*)alloc((size_t)Nn * 160 * 2);  // 80 MiB, stride 160
    int* cursor = deg;                     // deg dead after scan1
    unsigned short* xb = (unsigned short*)h2; // xb dead before L2 writes h2

    // head scratch aliases h1 (dead after layer-2 gather)
    size_t hoff = 0;
    auto halloc = [&](size_t bytes) -> void* {
        hoff = (hoff + 255) & ~(size_t)255;
        void* p = (char*)h1 + hoff;
        hoff += bytes;
        return p;
    };
    float* gpool = (float*)halloc((size_t)Bb * 312 * 4);
    float* g1    = (float*)halloc((size_t)Bb * 1024 * 4);
    float* xc    = (float*)halloc((size_t)Bb * 256 * 4);
    float* f1    = (float*)halloc((size_t)Bb * 1024 * 4);
    float* f2    = (float*)halloc((size_t)Bb * 512 * 4);
    float* C0    = (float*)halloc(128 * 4);
    float* Pbuf  = (float*)halloc((size_t)26 * 32 * 8 * 128 * 4);
    float* Tbuf  = (float*)halloc((size_t)26 * 1000 * 128 * 4);

    const int nb = (Nn + 255) / 256; // 977

    // x -> bf16 padded (into h2 region; consumed by L1 before h2 written)
    k_xprep<<<(Nn * 20 + 255) / 256, 256, 0, stream>>>(x, xb);

    // degree + dinv + CSR (by dst)
    hipMemsetAsync(deg, 0, (size_t)Nn * 4, stream);
    k_deg<<<(Ee + 255) / 256, 256, 0, stream>>>(dst, deg);
    k_dinv<<<nb, 256, 0, stream>>>(deg, dinv);
    k_scan1<<<nb, 256, 0, stream>>>(deg, rp, bsum);
    k_scan2<<<1, 1024, 0, stream>>>(bsum, nb);
    k_scan3<<<nb, 256, 0, stream>>>(rp, cursor, bsum);
    k_scatter<<<(Ee + 255) / 256, 256, 0, stream>>>(src, dst, dinv, cursor, col, enorm);

    // pack W into MFMA B-fragment layout (tiny)
    k_wprep<78, 78, 96, 80><<<dim3(5, 3), 64, 0, stream>>>(W1, Wb1);
    k_wprep<78, 156, 96, 160><<<dim3(10, 3), 64, 0, stream>>>(W2, Wb2);
    k_wprep<156, 312, 160, 320><<<dim3(20, 5), 64, 0, stream>>>(W3, Wb3);

    // GCN layers (gather -> MFMA; layer 3 fuses max-pool); NS=2 slots/thread
    const int g64 = (Nn + 63) / 64; // 3907 (last block ragged: 16 rows)
    const int g32 = (Nn + 31) / 32; // 7813 (last block ragged: 16 rows)
    k_gcn<80, 96, 78, 80, 80, false, 64><<<g64, 320, 0, stream>>>(
        (const __hip_bfloat16*)xb, rp, col, enorm, dinv, Wb1, b1, h1, (float*)nullptr);
    k_gcn<80, 96, 156, 160, 160, false, 64><<<g64, 320, 0, stream>>>(
        h1, rp, col, enorm, dinv, Wb2, b2, h2, (float*)nullptr);
    // ---- h1 dead from here; alias region becomes head scratch ----
    hipMemsetAsync(gpool, 0, (size_t)Bb * 312 * 4, stream);
    k_gcn<160, 160, 312, 320, 0, true, 32><<<g32, 320, 0, stream>>>(
        h2, rp, col, enorm, dinv, Wb3, b3, (__hip_bfloat16*)nullptr, gpool);

    // protein branch (linearized)
    hipMemsetAsync(C0, 0, 128 * 4, stream);
    hipMemsetAsync(xc, 0, (size_t)Bb * 256 * 4, stream);
    k_P<<<dim3(26, 32), 128, 0, stream>>>(emb, fcxt_w, Pbuf);
    k_T<<<dim3(125, 26), 128, 0, stream>>>(conv_w, Pbuf, Tbuf);
    k_C0<<<32, 128, 0, stream>>>(fcxt_w, fcxt_b, conv_b, C0);
    k_xt<8><<<dim3(Bb, 8), 128, 0, stream>>>(target, Tbuf, C0, xc);

    // graph head
    k_fc<312, 1024, 1, true, 256><<<dim3(4, Bb, 1), 256, 0, stream>>>(gpool, fcg1_w, fcg1_b, g1, 1024, 0);
    k_fc<1024, 128, 2, false, 128><<<dim3(1, Bb, 2), 128, 0, stream>>>(g1, fcg2_w, fcg2_b, xc, 256, 0);

    // fusion head
    k_fc<256, 1024, 1, true, 256><<<dim3(4, Bb, 1), 256, 0, stream>>>(xc, fc1_w, fc1_b, f1, 1024, 0);
    k_fc<1024, 512, 1, true, 256><<<dim3(2, Bb, 1), 256, 0, stream>>>(f1, fc2_w, fc2_b, f2, 512, 0);
    k_out<<<Bb, 64, 0, stream>>>(f2, out_w, out_b, (float*)d_out);
}

// Round 10
// 832.317 us; speedup vs baseline: 1.1854x; 1.1320x over previous
//
#include <hip/hip_runtime.h>
#include <hip/hip_bf16.h>

#define DEV_INLINE __device__ __forceinline__

static constexpr int Nn = 250000;   // nodes
static constexpr int Ee = 1000000;  // edges
static constexpr int Bb = 500;      // graphs
static constexpr int NPB = Nn / Bb; // nodes per graph (batch = repeat(arange(B), N/B))

typedef __attribute__((ext_vector_type(8))) short short8;          // 8 bf16 (4 VGPRs)
typedef __attribute__((ext_vector_type(8))) unsigned short ushort8v;
typedef __attribute__((ext_vector_type(4))) unsigned int uint4v;   // 16B load (4 VGPRs)
typedef __attribute__((ext_vector_type(4))) float f32x4;           // MFMA acc
typedef __attribute__((ext_vector_type(2))) float f32x2;           // packed f32 pair

DEV_INLINE __hip_bfloat16 f2b(float v) { return __float2bfloat16(v); }
DEV_INLINE unsigned short f2bu(float v) {
    __hip_bfloat16 h = __float2bfloat16(v);
    return __builtin_bit_cast(unsigned short, h);
}

// one u32 = two bf16 (elem k low, elem k+1 high) -> two f32, 2 VALU ops
DEV_INLINE f32x2 pairf(unsigned u) {
    f32x2 r;
    r.x = __uint_as_float(u << 16);
    r.y = __uint_as_float(u & 0xffff0000u);
    return r;
}
DEV_INLINE f32x2 fma2(f32x2 a, f32x2 b, f32x2 c) {
#if __has_builtin(__builtin_elementwise_fma)
    return __builtin_elementwise_fma(a, b, c);   // v_pk_fma_f32
#else
    return a * b + c;
#endif
}

// ---------------- degree / dinv / CSR build ----------------
__global__ void k_deg(const int* __restrict__ dst, int* __restrict__ deg) {
    int i = blockIdx.x * 256 + threadIdx.x;
    if (i < Ee) atomicAdd(&deg[dst[i]], 1);
}

// scan1 fused with dinv computation (deg already in-register here)
__global__ __launch_bounds__(256) void k_scan1(const int* __restrict__ deg,
                                               int* __restrict__ rp,
                                               int* __restrict__ bsum,
                                               float* __restrict__ dinv) {
    __shared__ int s[256];
    int t = threadIdx.x;
    int i = blockIdx.x * 256 + t;
    int v = (i < Nn) ? deg[i] : 0;
    if (i < Nn) dinv[i] = rsqrtf((float)v + 1.0f);
    s[t] = v;
    __syncthreads();
    for (int off = 1; off < 256; off <<= 1) {
        int x = (t >= off) ? s[t - off] : 0;
        __syncthreads();
        s[t] += x;
        __syncthreads();
    }
    if (i < Nn) rp[i] = s[t] - v;
    if (t == 255) bsum[blockIdx.x] = s[255];
}

__global__ __launch_bounds__(1024) void k_scan2(int* __restrict__ bsum, int nb) {
    __shared__ int s[1024];
    int t = threadIdx.x;
    int v = (t < nb) ? bsum[t] : 0;
    s[t] = v;
    __syncthreads();
    for (int off = 1; off < 1024; off <<= 1) {
        int x = (t >= off) ? s[t - off] : 0;
        __syncthreads();
        s[t] += x;
        __syncthreads();
    }
    if (t < nb) bsum[t] = s[t] - v;
}

__global__ void k_scan3(int* __restrict__ rp, int* __restrict__ cursor,
                        const int* __restrict__ bsum) {
    int i = blockIdx.x * 256 + threadIdx.x;
    if (i < Nn) {
        int v = rp[i] + bsum[blockIdx.x];
        rp[i] = v;
        cursor[i] = v;
    }
    if (i == 0) rp[Nn] = Ee;
}

__global__ void k_scatter(const int* __restrict__ src, const int* __restrict__ dst,
                          const float* __restrict__ dinv, int* __restrict__ cursor,
                          int* __restrict__ col, float* __restrict__ enorm) {
    int i = blockIdx.x * 256 + threadIdx.x;
    if (i >= Ee) return;
    int s = src[i], d = dst[i];
    int pos = atomicAdd(&cursor[d], 1);
    col[pos] = s;
    enorm[pos] = dinv[s] * dinv[d];
}

// ---------------- x (fp32, 78) -> xb (bf16, stride 80, zero-padded) ----------------
__global__ void k_xprep(const float* __restrict__ x, unsigned short* __restrict__ xb) {
    int gid = blockIdx.x * 256 + threadIdx.x; // Nn*20 threads, 4 features each
    if (gid >= Nn * 20) return;
    int i = gid / 20;
    int c = gid - 20 * i;
    int k = 4 * c;
    const float* xp = x + (size_t)i * 78;
    ushort4 u;
    u.x = (k + 0 < 78) ? f2bu(xp[k + 0]) : (unsigned short)0;
    u.y = (k + 1 < 78) ? f2bu(xp[k + 1]) : (unsigned short)0;
    u.z = (k + 2 < 78) ? f2bu(xp[k + 2]) : (unsigned short)0;
    u.w = (k + 3 < 78) ? f2bu(xp[k + 3]) : (unsigned short)0;
    *(ushort4*)&xb[(size_t)i * 80 + k] = u;
}

// ---------------- W -> bf16 B-fragment pack for mfma_f32_16x16x32_bf16 ----------------
// lane l holds B[k = (l>>4)*8 + j + ks*32][n = nt*16 + (l&15)], j=0..7; zero-pad.
template <int K, int F, int KP, int FP>
__global__ __launch_bounds__(64) void k_wprep(const float* __restrict__ W,
                                              unsigned short* __restrict__ Wb) {
    constexpr int KSTEPS = KP / 32;
    const int nt = blockIdx.x, ks = blockIdx.y;
    const int l = threadIdx.x;
    const int n = nt * 16 + (l & 15);
    unsigned short* o = Wb + ((size_t)(nt * KSTEPS + ks) * 64 + l) * 8;
#pragma unroll
    for (int j = 0; j < 8; ++j) {
        const int k = (l >> 4) * 8 + j + ks * 32;
        o[j] = (k < K && n < F) ? f2bu(W[(size_t)k * F + n]) : (unsigned short)0;
    }
}

// ---------------- fused GCN layer: CSR gather (16B/lane) -> bf16 LDS -> MFMA ----------
// in: bf16 rows of stride KIN (zero-padded); out: bf16 rows of stride SOUT (pads zeroed).
// MAXROWS rows per block; CPR*MAXROWS == BD so each thread owns exactly one
// (row, 8-feature chunk) slot. Accumulate in packed f32 pairs (v_pk_fma_f32) --
// f32 accumulation REQUIRED (fp16 accum failed at 0.31 absmax).
// Session conclusion: gather is random-row fetch THROUGHPUT bound (~2.4 TB/s eff.);
// width-8 (r7), NS=2 chains (r9), DS-atomics (r1), MFMA-agg (r4) all lose or tie.
template <int KIN, int KP, int F, int FP, int SOUT, bool POOL, int MAXROWS>
__global__ __launch_bounds__(320, 8) void k_gcn(const __hip_bfloat16* __restrict__ in_,
                                                const int* __restrict__ rp,
                                                const int* __restrict__ col,
                                                const float* __restrict__ enorm,
                                                const float* __restrict__ dinv,
                                                const unsigned short* __restrict__ Wb,
                                                const float* __restrict__ bias,
                                                __hip_bfloat16* __restrict__ out,
                                                float* __restrict__ gpool) {
    constexpr int BD = 320, WAVES = 5;
    constexpr int CPR = KIN / 8;       // 16B chunks per row
    constexpr int ECAP = 16 * MAXROWS;
    constexpr int KSTEPS = KP / 32;
    constexpr int NT = FP / 16;
    constexpr int TPW = NT / WAVES;
    static_assert(KIN % 8 == 0 && KP % 32 == 0 && KP >= KIN && FP % (16 * WAVES) == 0, "pad");
    static_assert(MAXROWS % 16 == 0, "row tiles");
    static_assert(!POOL || MAXROWS == 16, "pool path assumes 16 rows");
    static_assert(CPR * MAXROWS == BD, "one slot per thread");
    const unsigned short* in = (const unsigned short*)in_;

    __shared__ alignas(16) unsigned short sh[MAXROWS * KP];
    __shared__ int sRp[MAXROWS + 1];
    __shared__ int sCol[ECAP];
    __shared__ float sEn[ECAP];

    const int i0 = blockIdx.x * MAXROWS;
    const int rows = min(MAXROWS, Nn - i0);       // ragged last block (L1/L2)
    const int t = threadIdx.x;
    const int slots = rows * CPR;
    const bool act = (t < slots);

    // ---- hoisted independent loads for this thread's slot (overlap metadata latency) ----
    const int r = t / CPR;
    const int c = t - r * CPR;
    const size_t coff = (size_t)8 * c;
    uint4v selfv = {0u, 0u, 0u, 0u};
    float selfw = 0.f;
    if (act) {
        const int i = i0 + r;
        selfv = *(const uint4v*)(in + (size_t)i * KIN + coff);
        const float di = dinv[i];
        selfw = di * di;
    }

    if (t <= rows) sRp[t] = rp[i0 + t];
    const int base = rp[i0];
    const int ne = rp[i0 + rows] - base;
    const bool fit = (ne <= ECAP);
    if (fit) {
        for (int e = t; e < ne; e += BD) {
            sCol[e] = col[base + e];
            sEn[e] = enorm[base + e];
        }
    }
    if constexpr (KP > KIN) { // zero LDS k-pad region
        for (int e = t; e < MAXROWS * (KP - KIN); e += BD) {
            const int rr = e / (KP - KIN);
            sh[rr * KP + KIN + (e - rr * (KP - KIN))] = 0;
        }
    }
    __syncthreads();

    // --- gather: one (row, 8-feature chunk) slot per thread, masked 4-wide rounds ---
    if (act) {
        f32x2 acc2[4];
#pragma unroll
        for (int q = 0; q < 4; ++q) acc2[q] = pairf(selfv[q]) * selfw;

        const int e0a = sRp[r], e1a = sRp[r + 1];
        if (fit) {
            int j = e0a - base;
            const int jend = e1a - base;
            const int nit = (jend - j + 3) >> 2;       // ceil(deg/4) full-width rounds
            for (int it = 0; it < nit; ++it, j += 4) {
                const int jm = jend - 1;
                const int j1 = min(j + 1, jm), j2 = min(j + 2, jm), j3 = min(j + 3, jm);
                const int n0 = sCol[j], n1 = sCol[j1], n2 = sCol[j2], n3 = sCol[j3];
                const float w0 = sEn[j];
                const float w1 = (j + 1 < jend) ? sEn[j1] : 0.f;
                const float w2 = (j + 2 < jend) ? sEn[j2] : 0.f;
                const float w3 = (j + 3 < jend) ? sEn[j3] : 0.f;
                uint4v a0 = *(const uint4v*)(in + (size_t)n0 * KIN + coff);
                uint4v a1 = *(const uint4v*)(in + (size_t)n1 * KIN + coff);
                uint4v a2 = *(const uint4v*)(in + (size_t)n2 * KIN + coff);
                uint4v a3 = *(const uint4v*)(in + (size_t)n3 * KIN + coff);
                const f32x2 w0v = {w0, w0}, w1v = {w1, w1}, w2v = {w2, w2}, w3v = {w3, w3};
#pragma unroll
                for (int q = 0; q < 4; ++q) {
                    acc2[q] = fma2(pairf(a0[q]), w0v, acc2[q]);
                    acc2[q] = fma2(pairf(a1[q]), w1v, acc2[q]);
                    acc2[q] = fma2(pairf(a2[q]), w2v, acc2[q]);
                    acc2[q] = fma2(pairf(a3[q]), w3v, acc2[q]);
                }
            }
        } else { // overflow fallback: stream metadata from global
            for (int j = e0a; j < e1a; ++j) {
                const int n = col[j];
                const float wv = enorm[j];
                const f32x2 wvv = {wv, wv};
                uint4v a = *(const uint4v*)(in + (size_t)n * KIN + coff);
#pragma unroll
                for (int q = 0; q < 4; ++q) acc2[q] = fma2(pairf(a[q]), wvv, acc2[q]);
            }
        }
        ushort8v o;
#pragma unroll
        for (int q = 0; q < 4; ++q) {
            o[2 * q + 0] = f2bu(acc2[q].x);
            o[2 * q + 1] = f2bu(acc2[q].y);
        }
        *(ushort8v*)&sh[r * KP + 8 * c] = o;
    }
    __syncthreads();

    // --- MFMA phase: row tiles of 16 ---
    const int w = t >> 6, lane = t & 63;
    const int arow = lane & 15, aquad = lane >> 4;
    const int nrt = rows >> 4;

    for (int rt = 0; rt < nrt; ++rt) {
        short8 afr[KSTEPS];
#pragma unroll
        for (int ks = 0; ks < KSTEPS; ++ks)
            afr[ks] = *(const short8*)&sh[(rt * 16 + arow) * KP + aquad * 8 + ks * 32];

        const int ir0 = i0 + rt * 16;
        const bool uni = (ir0 / NPB) == ((ir0 + 15) / NPB); // tile within one graph

#pragma unroll
        for (int nti = 0; nti < TPW; ++nti) {
            const int nt = w * TPW + nti;
            const short8* bp = (const short8*)Wb + (size_t)nt * KSTEPS * 64 + lane;
            f32x4 acc = {0.f, 0.f, 0.f, 0.f};
#pragma unroll
            for (int ks = 0; ks < KSTEPS; ++ks) {
                short8 bfr = bp[ks * 64];
                acc = __builtin_amdgcn_mfma_f32_16x16x32_bf16(afr[ks], bfr, acc, 0, 0, 0);
            }
            const int f = nt * 16 + arow; // C/D: col = lane&15, row = quad*4 + reg
            const int ib = ir0 + aquad * 4;
            if constexpr (!POOL) {
                if (f < F) {
                    const float bv = bias[f];
#pragma unroll
                    for (int rr = 0; rr < 4; ++rr)
                        out[(size_t)(ib + rr) * SOUT + f] = f2b(fmaxf(acc[rr] + bv, 0.f));
                } else if (f < SOUT) { // zero the pad columns
#pragma unroll
                    for (int rr = 0; rr < 4; ++rr)
                        out[(size_t)(ib + rr) * SOUT + f] = f2b(0.f);
                }
            } else {
                float m = 0.f, v[4];
                const float bv = (f < F) ? bias[f] : 0.f;
#pragma unroll
                for (int rr = 0; rr < 4; ++rr) {
                    v[rr] = fmaxf(acc[rr] + bv, 0.f);
                    m = fmaxf(m, v[rr]);
                }
                if (uni) {
                    // cross-quad max via shuffle (quads = lane blocks of 16), 1 atomic/f/block
                    m = fmaxf(m, __shfl_xor(m, 16));
                    m = fmaxf(m, __shfl_xor(m, 32));
                    if (aquad == 0 && f < F)
                        atomicMax((int*)&gpool[(ir0 / NPB) * F + f], __float_as_int(m));
                } else if (f < F) {
                    const int g0 = ib / NPB, g3 = (ib + 3) / NPB;
                    if (g0 == g3) {
                        atomicMax((int*)&gpool[g0 * F + f], __float_as_int(m));
                    } else {
#pragma unroll
                        for (int rr = 0; rr < 4; ++rr)
                            atomicMax((int*)&gpool[((ib + rr) / NPB) * F + f], __float_as_int(v[rr]));
                    }
                }
            }
        }
    }
}

// ---------------- FC: grid (FOUT/BD, Bb, KS); block-uniform input row ----------------
template <int K, int FOUT, int KS, bool RELU, int BD>
__global__ __launch_bounds__(BD) void k_fc(const float* __restrict__ in,
                                           const float* __restrict__ W,
                                           const float* __restrict__ bias,
                                           float* __restrict__ out,
                                           int ostride, int ooff) {
    static_assert(!(RELU && KS > 1), "cannot split K with fused ReLU");
    static_assert(K % KS == 0, "K must divide evenly");
    constexpr int KC = K / KS;
    const int j = blockIdx.x * BD + threadIdx.x;
    const int b = blockIdx.y;
    const int z = blockIdx.z;
    const float* __restrict__ inp = in + (size_t)b * K + z * KC;
    const float* __restrict__ Wp = W + (size_t)(z * KC) * FOUT + j;
    float acc = (z == 0) ? bias[j] : 0.f;
#pragma unroll 8
    for (int k = 0; k < KC; ++k) acc += inp[k] * Wp[(size_t)k * FOUT];
    float* dst = &out[(size_t)b * ostride + ooff + j];
    if (KS > 1) {
        atomicAdd(dst, acc);
    } else {
        *dst = RELU ? fmaxf(acc, 0.f) : acc;
    }
}

// ============ protein branch, linearized: xt[b,j] = C0[j] + sum_i T[t[b,i]][i][j] ============
__global__ __launch_bounds__(128) void k_P(const float* __restrict__ emb,
                                           const float* __restrict__ fcxt_w,
                                           float* __restrict__ P) {
    const int v = blockIdx.x, o = blockIdx.y;
    const int j = threadIdx.x;
    __shared__ float se[128];
    se[j] = emb[v * 128 + j];
    __syncthreads();
    float acc[8];
#pragma unroll
    for (int k = 0; k < 8; ++k) acc[k] = 0.f;
    const float* fw = fcxt_w + (size_t)(o * 121) * 128 + j;
#pragma unroll 4
    for (int h = 0; h < 121; ++h) {
        const float f = fw[(size_t)h * 128];
#pragma unroll
        for (int k = 0; k < 8; ++k) acc[k] += se[h + k] * f;
    }
    float* Pp = P + ((size_t)(v * 32 + o) * 8) * 128 + j;
#pragma unroll
    for (int k = 0; k < 8; ++k) Pp[(size_t)k * 128] = acc[k];
}

__global__ __launch_bounds__(128) void k_T(const float* __restrict__ convw,
                                           const float* __restrict__ P,
                                           float* __restrict__ T) {
    const int i0 = blockIdx.x * 8;
    const int v = blockIdx.y;
    const int t = threadIdx.x;
    __shared__ float wt[8 * 256];
    for (int e = t; e < 2048; e += 128) {
        const int r = e >> 8;
        const int kk = e & 255;
        wt[e] = convw[(size_t)(kk >> 3) * 8000 + (size_t)(i0 + r) * 8 + (kk & 7)];
    }
    __syncthreads();
    float acc[8];
#pragma unroll
    for (int r = 0; r < 8; ++r) acc[r] = 0.f;
    const float* Pp = P + (size_t)v * 256 * 128 + t;
#pragma unroll 2
    for (int kk = 0; kk < 256; ++kk) {
        const float pv = Pp[(size_t)kk * 128];
#pragma unroll
        for (int r = 0; r < 8; ++r) acc[r] += wt[r * 256 + kk] * pv;
    }
    float* Tp = T + ((size_t)v * 1000 + i0) * 128 + t;
#pragma unroll
    for (int r = 0; r < 8; ++r) Tp[(size_t)r * 128] = acc[r];
}

__global__ __launch_bounds__(128) void k_C0(const float* __restrict__ fcxt_w,
                                            const float* __restrict__ fcxt_b,
                                            const float* __restrict__ convb,
                                            float* __restrict__ C0) {
    const int o = blockIdx.x;
    const int j = threadIdx.x;
    float acc = 0.f;
    const float* fw = fcxt_w + (size_t)(o * 121) * 128 + j;
#pragma unroll 4
    for (int h = 0; h < 121; ++h) acc += fw[(size_t)h * 128];
    acc *= convb[o];
    if (o == 0) acc += fcxt_b[j];
    atomicAdd(&C0[j], acc);
}

template <int ZS>
__global__ __launch_bounds__(128) void k_xt(const int* __restrict__ target,
                                            const float* __restrict__ T,
                                            const float* __restrict__ C0,
                                            float* __restrict__ xc) {
    constexpr int CH = 1000 / ZS;
    const int b = blockIdx.x;
    const int z = blockIdx.y;
    const int j = threadIdx.x;
    const int* tg = target + b * 1000 + z * CH;
    float acc = (z == 0) ? C0[j] : 0.f;
    int i = 0;
    for (; i + 4 <= CH; i += 4) {
        const int v0 = tg[i + 0], v1 = tg[i + 1], v2 = tg[i + 2], v3 = tg[i + 3];
        const int ib = z * CH + i;
        acc += T[((size_t)v0 * 1000 + ib + 0) * 128 + j]
             + T[((size_t)v1 * 1000 + ib + 1) * 128 + j]
             + T[((size_t)v2 * 1000 + ib + 2) * 128 + j]
             + T[((size_t)v3 * 1000 + ib + 3) * 128 + j];
    }
    for (; i < CH; ++i) { // tail
        acc += T[((size_t)tg[i] * 1000 + z * CH + i) * 128 + j];
    }
    atomicAdd(&xc[(size_t)b * 256 + 128 + j], acc);
}

// ---------------- final projection: one wave per graph, shuffle reduction ----------------
__global__ __launch_bounds__(64) void k_out(const float* __restrict__ in,
                                            const float* __restrict__ w,
                                            const float* __restrict__ ob,
                                            float* __restrict__ out) {
    const int b = blockIdx.x;
    const int lane = threadIdx.x;
    const float* p = in + (size_t)b * 512;
    float acc = 0.f;
#pragma unroll
    for (int i = 0; i < 8; ++i) acc += p[lane + 64 * i] * w[lane + 64 * i];
    for (int off = 32; off > 0; off >>= 1) acc += __shfl_down(acc, off);
    if (lane == 0) out[b] = acc + ob[0];
}

extern "C" void kernel_launch(void* const* d_in, const int* in_sizes, int n_in,
                              void* d_out, int out_size, void* d_ws, size_t ws_size,
                              hipStream_t stream) {
    (void)in_sizes; (void)n_in; (void)out_size; (void)ws_size;
    const float* x      = (const float*)d_in[0];
    const int* ei       = (const int*)d_in[1];
    const int* target   = (const int*)d_in[3];
    const float* W1     = (const float*)d_in[4];
    const float* b1     = (const float*)d_in[5];
    const float* W2     = (const float*)d_in[6];
    const float* b2     = (const float*)d_in[7];
    const float* W3     = (const float*)d_in[8];
    const float* b3     = (const float*)d_in[9];
    const float* fcg1_w = (const float*)d_in[10];
    const float* fcg1_b = (const float*)d_in[11];
    const float* fcg2_w = (const float*)d_in[12];
    const float* fcg2_b = (const float*)d_in[13];
    const float* emb    = (const float*)d_in[14];
    const float* conv_w = (const float*)d_in[15];
    const float* conv_b = (const float*)d_in[16];
    const float* fcxt_w = (const float*)d_in[17];
    const float* fcxt_b = (const float*)d_in[18];
    const float* fc1_w  = (const float*)d_in[19];
    const float* fc1_b  = (const float*)d_in[20];
    const float* fc2_w  = (const float*)d_in[21];
    const float* fc2_b  = (const float*)d_in[22];
    const float* out_w  = (const float*)d_in[23];
    const float* out_b  = (const float*)d_in[24];

    const int* src = ei;
    const int* dst = ei + Ee;

    // ---- workspace layout (~131 MiB; xb aliases h2, head scratch aliases h1) ----
    size_t off = 0;
    auto alloc = [&](size_t bytes) -> void* {
        off = (off + 255) & ~(size_t)255;
        void* p = (char*)d_ws + off;
        off += bytes;
        return p;
    };
    int*   deg    = (int*)alloc((size_t)Nn * 4);
    float* dinv   = (float*)alloc((size_t)Nn * 4);
    int*   rp     = (int*)alloc((size_t)(Nn + 1) * 4);
    int*   col    = (int*)alloc((size_t)Ee * 4);
    float* enorm  = (float*)alloc((size_t)Ee * 4);
    int*   bsum   = (int*)alloc(1024 * 4);
    unsigned short* Wb1 = (unsigned short*)alloc((size_t)5 * 3 * 64 * 8 * 2);
    unsigned short* Wb2 = (unsigned short*)alloc((size_t)10 * 3 * 64 * 8 * 2);
    unsigned short* Wb3 = (unsigned short*)alloc((size_t)20 * 5 * 64 * 8 * 2);
    __hip_bfloat16* h1 = (__hip_bfloat16*)alloc((size_t)Nn * 80 * 2);   // 40 MiB, stride 80
    __hip_bfloat16* h2 = (__hip_bfloat16*)alloc((size_t)Nn * 160 * 2);  // 80 MiB, stride 160
    int* cursor = deg;                     // deg dead after scan1
    unsigned short* xb = (unsigned short*)h2; // xb dead before L2 writes h2

    // head scratch aliases h1 (dead after layer-2 gather)
    size_t hoff = 0;
    auto halloc = [&](size_t bytes) -> void* {
        hoff = (hoff + 255) & ~(size_t)255;
        void* p = (char*)h1 + hoff;
        hoff += bytes;
        return p;
    };
    float* gpool = (float*)halloc((size_t)Bb * 312 * 4);
    float* g1    = (float*)halloc((size_t)Bb * 1024 * 4);
    float* xc    = (float*)halloc((size_t)Bb * 256 * 4);
    float* f1    = (float*)halloc((size_t)Bb * 1024 * 4);
    float* f2    = (float*)halloc((size_t)Bb * 512 * 4);
    float* C0    = (float*)halloc(128 * 4);
    float* Pbuf  = (float*)halloc((size_t)26 * 32 * 8 * 128 * 4);
    float* Tbuf  = (float*)halloc((size_t)26 * 1000 * 128 * 4);

    const int nb = (Nn + 255) / 256; // 977

    // x -> bf16 padded (into h2 region; consumed by L1 before h2 written)
    k_xprep<<<(Nn * 20 + 255) / 256, 256, 0, stream>>>(x, xb);

    // degree + dinv + CSR (by dst); dinv fused into scan1
    hipMemsetAsync(deg, 0, (size_t)Nn * 4, stream);
    k_deg<<<(Ee + 255) / 256, 256, 0, stream>>>(dst, deg);
    k_scan1<<<nb, 256, 0, stream>>>(deg, rp, bsum, dinv);
    k_scan2<<<1, 1024, 0, stream>>>(bsum, nb);
    k_scan3<<<nb, 256, 0, stream>>>(rp, cursor, bsum);
    k_scatter<<<(Ee + 255) / 256, 256, 0, stream>>>(src, dst, dinv, cursor, col, enorm);

    // pack W into MFMA B-fragment layout (tiny)
    k_wprep<78, 78, 96, 80><<<dim3(5, 3), 64, 0, stream>>>(W1, Wb1);
    k_wprep<78, 156, 96, 160><<<dim3(10, 3), 64, 0, stream>>>(W2, Wb2);
    k_wprep<156, 312, 160, 320><<<dim3(20, 5), 64, 0, stream>>>(W3, Wb3);

    // GCN layers (gather -> MFMA; layer 3 fuses max-pool)
    const int g32 = (Nn + 31) / 32; // 7813 (last block ragged: 16 rows)
    k_gcn<80, 96, 78, 80, 80, false, 32><<<g32, 320, 0, stream>>>(
        (const __hip_bfloat16*)xb, rp, col, enorm, dinv, Wb1, b1, h1, (float*)nullptr);
    k_gcn<80, 96, 156, 160, 160, false, 32><<<g32, 320, 0, stream>>>(
        h1, rp, col, enorm, dinv, Wb2, b2, h2, (float*)nullptr);
    // ---- h1 dead from here; alias region becomes head scratch ----
    hipMemsetAsync(gpool, 0, (size_t)Bb * 312 * 4, stream);
    k_gcn<160, 160, 312, 320, 0, true, 16><<<Nn / 16, 320, 0, stream>>>(
        h2, rp, col, enorm, dinv, Wb3, b3, (__hip_bfloat16*)nullptr, gpool);

    // protein branch (linearized)
    hipMemsetAsync(C0, 0, 128 * 4, stream);
    hipMemsetAsync(xc, 0, (size_t)Bb * 256 * 4, stream);
    k_P<<<dim3(26, 32), 128, 0, stream>>>(emb, fcxt_w, Pbuf);
    k_T<<<dim3(125, 26), 128, 0, stream>>>(conv_w, Pbuf, Tbuf);
    k_C0<<<32, 128, 0, stream>>>(fcxt_w, fcxt_b, conv_b, C0);
    k_xt<8><<<dim3(Bb, 8), 128, 0, stream>>>(target, Tbuf, C0, xc);

    // graph head
    k_fc<312, 1024, 1, true, 256><<<dim3(4, Bb, 1), 256, 0, stream>>>(gpool, fcg1_w, fcg1_b, g1, 1024, 0);
    k_fc<1024, 128, 2, false, 128><<<dim3(1, Bb, 2), 128, 0, stream>>>(g1, fcg2_w, fcg2_b, xc, 256, 0);

    // fusion head
    k_fc<256, 1024, 1, true, 256><<<dim3(4, Bb, 1), 256, 0, stream>>>(xc, fc1_w, fc1_b, f1, 1024, 0);
    k_fc<1024, 512, 1, true, 256><<<dim3(2, Bb, 1), 256, 0, stream>>>(f1, fc2_w, fc2_b, f2, 512, 0);
    k_out<<<Bb, 64, 0, stream>>>(f2, out_w, out_b, (float*)d_out);
}